// Round 17
// baseline (5617.086 us; speedup 1.0000x reference)
//
#include <hip/hip_runtime.h>
#include <cstdio>
#include <cstdint>

#define TT 1024
#define DD 1024
#define HH 1024
#define NN 32
#define G4 4096

using bf16x8   = __attribute__((ext_vector_type(8))) __bf16;
using f32x4    = __attribute__((ext_vector_type(4))) float;
using uint32x4 = __attribute__((ext_vector_type(4))) unsigned int;

typedef const __attribute__((address_space(1))) void* gas_cp;
typedef __attribute__((address_space(3))) void* las_p;

__device__ __forceinline__ unsigned short f2bf(float f) {
  unsigned int u = __builtin_bit_cast(unsigned int, f);
  u = u + 0x7fffu + ((u >> 16) & 1u);
  return (unsigned short)(u >> 16);
}
__device__ __forceinline__ float bf2f(unsigned short s) {
  unsigned int u = ((unsigned int)s) << 16;
  return __builtin_bit_cast(float, u);
}
__device__ __forceinline__ float sigm(float x) { return 1.f / (1.f + __expf(-x)); }
__device__ __forceinline__ float tanh_f(float x) {
  float a = fabsf(x);
  float e = __expf(-2.f * a);
  float r = (1.f - e) / (1.f + e);
  return x < 0.f ? -r : r;
}

// ---- cast x (f32 -> bf16)
__global__ void cast_bf4(const float4* __restrict__ in, uint2* __restrict__ o, int n4) {
  int i = blockIdx.x * 256 + threadIdx.x;
  if (i < n4) {
    float4 v = in[i];
    uint2 r;
    r.x = (unsigned int)f2bf(v.x) | ((unsigned int)f2bf(v.y) << 16);
    r.y = (unsigned int)f2bf(v.z) | ((unsigned int)f2bf(v.w) << 16);
    o[i] = r;
  }
}

// ---- transpose+cast: in [R][C] f32 -> out [C][R] bf16
__global__ void transp_cast(const float* __restrict__ in, unsigned short* __restrict__ outT,
                            int R, int C) {
  __shared__ unsigned short t[64][65];
  int nbc = C >> 6;
  int tc = blockIdx.x % nbc, tr = blockIdx.x / nbc;
  int r0 = tr << 6, c0 = tc << 6;
  for (int i = threadIdx.x; i < 4096; i += 256) {
    int r = i >> 6, c = i & 63;
    t[c][r] = f2bf(in[(size_t)(r0 + r) * C + c0 + c]);
  }
  __syncthreads();
  for (int i = threadIdx.x; i < 4096; i += 256) {
    int c = i >> 6, r = i & 63;
    outT[(size_t)(c0 + c) * R + r0 + r] = t[c][r];
  }
}

// ---- pack h0 into tagged u32 buffer (tag = 0)
__global__ void pack_h0(const float* __restrict__ in, unsigned int* __restrict__ o) {
  int i = blockIdx.x * 256 + threadIdx.x;
  o[i] = (unsigned int)f2bf(in[i]);
}

// ---- Phase 1: xw packed as [t][cl][jw][r][jc][g] bf16 (u64 of 4 gates per cell)
#define BM 128
#define BN 128
#define BK 64

__launch_bounds__(256, 2)
__global__ void gemm_xw(const unsigned short* __restrict__ A,   // [32768][1024] bf16 (m = n*T+t)
                        const unsigned short* __restrict__ B,   // [4096][1024] bf16 (WxT)
                        const float* __restrict__ bias,         // [4096]
                        unsigned short* __restrict__ C)         // [1024][8][32][4][32][4] bf16
{
  __shared__ alignas(16) unsigned short As[BM * BK];
  __shared__ alignas(16) unsigned short Bs[BN * BK];
  int bid = blockIdx.x;
  int swz = (bid & 7) * 1024 + (bid >> 3);
  int grp = swz >> 8;
  int loc = swz & 255;
  int tm = (grp << 3) + (loc & 7);
  int tn = loc >> 3;
  int tid = threadIdx.x;
  int w = tid >> 6, lane = tid & 63;
  int wr = w >> 1, wc = w & 1;

  f32x4 acc[4][4] = {};

  const size_t rowA0 = (size_t)tm * BM;
  const size_t colB0 = (size_t)tn * BN;

  for (int k0 = 0; k0 < DD; k0 += BK) {
    #pragma unroll
    for (int i = 0; i < 4; ++i) {
      int chunk = w * 4 + i;
      int p = chunk * 1024 + lane * 16;
      int row = p >> 7;
      int bo = p & 127;
      int gb = bo ^ ((row & 7) << 4);
      const char* ga = (const char*)(A + (rowA0 + row) * DD + k0) + gb;
      __builtin_amdgcn_global_load_lds((gas_cp)ga, (las_p)((char*)As + chunk * 1024), 16, 0, 0);
      const char* gB = (const char*)(B + (colB0 + row) * DD + k0) + gb;
      __builtin_amdgcn_global_load_lds((gas_cp)gB, (las_p)((char*)Bs + chunk * 1024), 16, 0, 0);
    }
    __syncthreads();

    #pragma unroll
    for (int ks = 0; ks < 2; ++ks) {
      bf16x8 af[4], bfr[4];
      #pragma unroll
      for (int mi = 0; mi < 4; ++mi) {
        int row = wr * 64 + mi * 16 + (lane & 15);
        int kb = (ks * 32 + ((lane >> 4) << 3)) * 2;
        af[mi] = *(const bf16x8*)((const char*)As + row * 128 + (kb ^ ((row & 7) << 4)));
      }
      #pragma unroll
      for (int ni = 0; ni < 4; ++ni) {
        int row = wc * 64 + ni * 16 + (lane & 15);
        int kb = (ks * 32 + ((lane >> 4) << 3)) * 2;
        bfr[ni] = *(const bf16x8*)((const char*)Bs + row * 128 + (kb ^ ((row & 7) << 4)));
      }
      #pragma unroll
      for (int mi = 0; mi < 4; ++mi)
        #pragma unroll
        for (int ni = 0; ni < 4; ++ni)
          acc[mi][ni] = __builtin_amdgcn_mfma_f32_16x16x32_bf16(af[mi], bfr[ni], acc[mi][ni], 0, 0, 0);
    }
    __syncthreads();
  }

  #pragma unroll
  for (int ni = 0; ni < 4; ++ni) {
    int col = (int)colB0 + wc * 64 + ni * 16 + (lane & 15);
    float bb = bias[col];
    int g = col >> 10, J = col & 1023;
    int jw2 = J >> 5, jc2 = J & 31;
    #pragma unroll
    for (int mi = 0; mi < 4; ++mi) {
      #pragma unroll
      for (int r = 0; r < 4; ++r) {
        size_t row = rowA0 + wr * 64 + mi * 16 + ((lane >> 4) << 2) + r;  // m = n*T + t
        size_t n2 = row >> 10, t2 = row & 1023;
        size_t cl = n2 >> 2, rr = n2 & 3;
        C[((((t2 * 8 + cl) * 32 + jw2) * 4 + rr) * 32 + jc2) * 4 + g] = f2bf(acc[mi][ni][r] + bb);
      }
    }
  }
}

// ---- Phase 2: 8 XCD-local clusters, 256 wgs x 512 threads.
// r14 protocol + 2-GROUP STAGGER: the cluster's 4 independent sample chains
// split into group A (rows 0-1) and B (rows 2-3). Pass order A(t),B(t),
// A(t+1),... — A's store->visibility latency hides under B's full pass.
// Per pass, only lanes l15 in {2G,2G+1} load/poll (same hq formula as r14);
// other lanes feed stale regs to MFMA whose red rows are never read this
// pass. red parity = G (compile-time). All poll/store cadence = r14 proven.
#define LDA0(dst, ptr, off) asm volatile("global_load_dwordx2 %0, %1, off offset:" #off " sc0" : "=v"(dst) : "v"(ptr))
#define LDA1(dst, ptr, off) asm volatile("global_load_dwordx2 %0, %1, off offset:" #off " sc0 sc1" : "=v"(dst) : "v"(ptr))
#define LDW(dst, addr, off) asm volatile("global_load_dwordx4 %0, %1, off offset:" #off : "=v"(dst) : "v"(addr))

#define POLLCHUNK(r0, r1, r2, r3, o0, o1, o2, o3)                              \
  { int rc_ = 0;                                                               \
    for (;;) {                                                                 \
      if (!(rc_ & 1)) { LDA0(r0,hq,o0); LDA0(r1,hq,o1); LDA0(r2,hq,o2); LDA0(r3,hq,o3); } \
      else            { LDA1(r0,hq,o0); LDA1(r1,hq,o1); LDA1(r2,hq,o2); LDA1(r3,hq,o3); } \
      asm volatile("s_waitcnt vmcnt(0)");                                      \
      __builtin_amdgcn_sched_barrier(0);                                       \
      unsigned long long bad_ = ((r0 & M64) ^ pat) | ((r1 & M64) ^ pat) |      \
                                ((r2 & M64) ^ pat) | ((r3 & M64) ^ pat);       \
      if (!__any(bad_ != 0)) break;                                            \
      __builtin_amdgcn_s_sleep(1);                                             \
      ++rc_;                                                                   \
    } }

#define RESOLVECHUNK(r0, r1, r2, r3, o0, o1, o2, o3)                           \
  { asm volatile("s_waitcnt vmcnt(0)");                                        \
    __builtin_amdgcn_sched_barrier(0);                                         \
    unsigned long long bad_ = ((r0 & M64) ^ pat) | ((r1 & M64) ^ pat) |        \
                              ((r2 & M64) ^ pat) | ((r3 & M64) ^ pat);         \
    if (__any(bad_ != 0)) {                                                    \
      __builtin_amdgcn_s_sleep(1);                                             \
      POLLCHUNK(r0, r1, r2, r3, o0, o1, o2, o3)                                \
    } }

#define PREFCHUNK(r0, r1, r2, r3, o0, o1, o2, o3)                              \
  { LDA0(r0,hq,o0); LDA0(r1,hq,o1); LDA0(r2,hq,o2); LDA0(r3,hq,o3); }

#define KSTEP(ks, a0, a1, a2, a3)                                              \
  { uint32x4 wv;                                                               \
    wv[0] = __builtin_amdgcn_perm((unsigned)((a0) >> 32), (unsigned)(a0), 0x05040100u); \
    wv[1] = __builtin_amdgcn_perm((unsigned)((a1) >> 32), (unsigned)(a1), 0x05040100u); \
    wv[2] = __builtin_amdgcn_perm((unsigned)((a2) >> 32), (unsigned)(a2), 0x05040100u); \
    wv[3] = __builtin_amdgcn_perm((unsigned)((a3) >> 32), (unsigned)(a3), 0x05040100u); \
    bf16x8 av = __builtin_bit_cast(bf16x8, wv);                                \
    _Pragma("unroll")                                                          \
    for (int tile = 0; tile < 8; ++tile)                                       \
      acc[tile] = __builtin_amdgcn_mfma_f32_16x16x32_bf16(av, Bf[tile][ks], acc[tile], 0, 0, 0); }

// one staggered pass for group G (G is a literal 0/1)
#define PASS(G, tv, cvar, xqvar, xqnvar)                                       \
  {                                                                            \
    const int hpar = (tv) & 1;                                                 \
    const unsigned int* hc = hbuf + (size_t)hpar * 32768 + cl * 4096;          \
    unsigned int* hn = hbuf + (size_t)(hpar ^ 1) * 32768 + cl * 4096;          \
    const unsigned long long pat =                                             \
        ((unsigned long long)(unsigned)(tv) << 16) |                           \
        ((unsigned long long)(unsigned)(tv) << 48);                            \
    const unsigned long long* hq =                                             \
        (const unsigned long long*)(hc + (size_t)r4row * 1024 + kq * 128 + q4 * 8); \
    const bool myld = ((l15 >> 1) == (G));                                     \
    f32x4 acc[8] = {};                                                         \
    if (myld) { POLLCHUNK(u0, u1, u2, u3, 0, 8, 16, 24)                        \
                PREFCHUNK(u4, u5, u6, u7, 128, 136, 144, 152) }                \
    KSTEP(0, u0, u1, u2, u3)                                                   \
    if (myld) { RESOLVECHUNK(u4, u5, u6, u7, 128, 136, 144, 152)               \
                PREFCHUNK(u8, u9, u10, u11, 256, 264, 272, 280) }              \
    KSTEP(1, u4, u5, u6, u7)                                                   \
    if (myld) { RESOLVECHUNK(u8, u9, u10, u11, 256, 264, 272, 280)             \
                PREFCHUNK(u12, u13, u14, u15, 384, 392, 400, 408) }            \
    KSTEP(2, u8, u9, u10, u11)                                                 \
    if (myld) { RESOLVECHUNK(u12, u13, u14, u15, 384, 392, 400, 408) }         \
    KSTEP(3, u12, u13, u14, u15)                                               \
    if (q4 == 0) {                                                             \
      _Pragma("unroll")                                                        \
      for (int tile = 0; tile < 8; ++tile)                                     \
        _Pragma("unroll")                                                      \
        for (int rg = 0; rg < 4; ++rg)                                         \
          red[G][kq][rg][tile * 16 + l15] = acc[tile][rg];                     \
    }                                                                          \
    __syncthreads();                                                           \
    if (epl) {                                                                 \
      int tp = ((tv) + 1 < TT) ? (tv) + 1 : 0;                                 \
      xqnvar = xw[(((size_t)tp * 8 + cl) * 32 + jw) * 128 + (G) * 64 + ecellg];\
    }                                                                          \
    if (epl) {                                                                 \
      const int er_ = (G) * 2 + erg;                                           \
      float s0 = 0.f, s1 = 0.f, s2 = 0.f, s3 = 0.f;                            \
      _Pragma("unroll")                                                        \
      for (int k2 = 0; k2 < 8; ++k2) {                                         \
        s0 += red[G][k2][er_][ej];                                             \
        s1 += red[G][k2][er_][32 + ej];                                        \
        s2 += red[G][k2][er_][64 + ej];                                        \
        s3 += red[G][k2][er_][96 + ej];                                        \
      }                                                                        \
      float ai  = s0 + bf2f((unsigned short)xqvar);                            \
      float af_ = s1 + bf2f((unsigned short)(xqvar >> 16));                    \
      float ao  = s2 + bf2f((unsigned short)(xqvar >> 32));                    \
      float ag  = s3 + bf2f((unsigned short)(xqvar >> 48));                    \
      float ig = sigm(ai), fg = sigm(af_), og = sigm(ao);                      \
      float gg = tanh_f(ag);                                                   \
      cvar = fg * cvar + ig * gg;                                              \
      float hv = og * tanh_f(cvar);                                            \
      unsigned int hp = (unsigned int)f2bf(hv) | ((unsigned int)((tv) + 1) << 16); \
      __hip_atomic_store(hn + (size_t)er_ * 1024 + j0 + ej, hp,                \
                         __ATOMIC_RELAXED, __HIP_MEMORY_SCOPE_AGENT);          \
      out[((size_t)(cl * 4 + er_) * TT + (tv)) * HH + j0 + ej] = hv;           \
    }                                                                          \
    xqvar = xqnvar;                                                            \
  }

__launch_bounds__(512, 1)
__global__ void lstm_rec(const unsigned long long* __restrict__ xw,  // [1024][8][32][128] u64
                         const unsigned short* __restrict__ WhT,     // [4096][1024] bf16
                         unsigned int* __restrict__ hbuf,            // [2][8][4][1024] u32 tagged
                         float* __restrict__ out)                    // [32][1024][1024] f32
{
  __shared__ float red[2][8][4][128];   // [group][kq][sample-row][gatecol] : 32 KB

  const int bid = blockIdx.x;
  const int cl = bid & 7;          // cluster (XCD via round-robin, perf-only)
  const int jw = bid >> 3;         // wg-in-cluster: h-cols jw*32..+32
  const int j0 = jw * 32;
  const int tid = threadIdx.x;
  const int lane = tid & 63;
  const int kq = tid >> 6;         // wave = K-eighth (128 k)
  const int l15 = lane & 15;
  const int q4 = lane >> 4;

  // ---- Wh slice -> registers via asm loads, once
  bf16x8 Bf[8][4];
  #pragma unroll
  for (int tile = 0; tile < 8; ++tile) {
    int cc = tile * 16 + l15;
    int gcol = (cc >> 5) * 1024 + j0 + (cc & 31);
    const unsigned short* wb = WhT + (size_t)gcol * HH + kq * 128 + q4 * 8;
    LDW(Bf[tile][0], wb, 0);
    LDW(Bf[tile][1], wb, 64);
    LDW(Bf[tile][2], wb, 128);
    LDW(Bf[tile][3], wb, 192);
  }
  asm volatile("s_waitcnt vmcnt(0)");

  const int r4row = lane & 3;           // loader row (= l15 for l15<4)
  const bool epl = (lane < 8);          // epilogue lanes: 8 per wave = 64 cells
  const int ecellg = kq * 8 + lane;     // 0..63 (valid when epl)
  const int erg = ecellg >> 5;          // 0..1 within group
  const int ej  = ecellg & 31;
  float cA = 0.f, cB = 0.f;
  const unsigned long long M64 = 0xFFFF0000FFFF0000ULL;

  unsigned long long u0=0,u1=0,u2=0,u3=0,u4=0,u5=0,u6=0,u7=0,
                     u8=0,u9=0,u10=0,u11=0,u12=0,u13=0,u14=0,u15=0;

  // prime xw for t=0, both groups
  unsigned long long xqA = 0, xqB = 0, xqnA = 0, xqnB = 0;
  if (epl) {
    xqA = xw[(((size_t)0 * 8 + cl) * 32 + jw) * 128 + ecellg];
    xqB = xw[(((size_t)0 * 8 + cl) * 32 + jw) * 128 + 64 + ecellg];
  }

  #pragma unroll 1
  for (int t = 0; t < TT; ++t) {
    PASS(0, t, cA, xqA, xqnA)
    PASS(1, t, cB, xqB, xqnB)
  }
}

extern "C" void kernel_launch(void* const* d_in, const int* in_sizes, int n_in,
                              void* d_out, int out_size, void* d_ws, size_t ws_size,
                              hipStream_t stream) {
  (void)in_sizes; (void)n_in; (void)out_size;
  const float* x  = (const float*)d_in[0];
  const float* h0 = (const float*)d_in[1];
  const float* Wx = (const float*)d_in[2];
  const float* Wh = (const float*)d_in[3];
  const float* b  = (const float*)d_in[4];
  float* out = (float*)d_out;

  char* ws = (char*)d_ws;
  size_t o_xw  = 0;
  size_t o_xbf = o_xw  + (size_t)32768 * 4096 * 2;  // xw   : 268435456 B
  size_t o_wxT = o_xbf + (size_t)32768 * 1024 * 2;  // xbf  :  67108864 B
  size_t o_whT = o_wxT + (size_t)4096 * 1024 * 2;   // WxT  :   8388608 B
  size_t o_hb  = o_whT + (size_t)4096 * 1024 * 2;   // WhT  :   8388608 B
  size_t need  = o_hb  + (size_t)2 * 32768 * 4;     // hbuf :    262144 B
  if (ws_size < need) {
    fprintf(stderr, "kernel_launch: ws_size %zu < needed %zu\n", ws_size, need);
    return;
  }
  unsigned short* xw  = (unsigned short*)(ws + o_xw);
  unsigned short* xbf = (unsigned short*)(ws + o_xbf);
  unsigned short* wxT = (unsigned short*)(ws + o_wxT);
  unsigned short* whT = (unsigned short*)(ws + o_whT);
  unsigned int*   hb  = (unsigned int*)(ws + o_hb);

  // kill stale tags from previous graph replay, then write h0 with tag 0
  hipMemsetAsync(hb, 0xFF, (size_t)2 * 32768 * 4, stream);
  pack_h0<<<128, 256, 0, stream>>>(h0, hb);
  cast_bf4<<<32768, 256, 0, stream>>>((const float4*)x, (uint2*)xbf, 33554432 / 4);
  transp_cast<<<1024, 256, 0, stream>>>(Wx, wxT, 1024, 4096);
  transp_cast<<<1024, 256, 0, stream>>>(Wh, whT, 1024, 4096);
  gemm_xw<<<8192, 256, 0, stream>>>(xbf, wxT, b, xw);

  void* args[] = { (void*)&xw, (void*)&whT, (void*)&hb, (void*)&out };
  hipLaunchCooperativeKernel(lstm_rec, dim3(256), dim3(512), args, 0, stream);
}

// Round 18
// 3977.242 us; speedup vs baseline: 1.4123x; 1.4123x over previous
//
#include <hip/hip_runtime.h>
#include <cstdio>
#include <cstdint>

#define TT 1024
#define DD 1024
#define HH 1024
#define NN 32
#define G4 4096

using bf16x8   = __attribute__((ext_vector_type(8))) __bf16;
using f32x4    = __attribute__((ext_vector_type(4))) float;
using uint32x4 = __attribute__((ext_vector_type(4))) unsigned int;

typedef const __attribute__((address_space(1))) void* gas_cp;
typedef __attribute__((address_space(3))) void* las_p;

__device__ __forceinline__ unsigned short f2bf(float f) {
  unsigned int u = __builtin_bit_cast(unsigned int, f);
  u = u + 0x7fffu + ((u >> 16) & 1u);
  return (unsigned short)(u >> 16);
}
__device__ __forceinline__ float bf2f(unsigned short s) {
  unsigned int u = ((unsigned int)s) << 16;
  return __builtin_bit_cast(float, u);
}
__device__ __forceinline__ float sigm(float x) { return 1.f / (1.f + __expf(-x)); }
__device__ __forceinline__ float tanh_f(float x) {
  float a = fabsf(x);
  float e = __expf(-2.f * a);
  float r = (1.f - e) / (1.f + e);
  return x < 0.f ? -r : r;
}

// ---- cast x (f32 -> bf16)
__global__ void cast_bf4(const float4* __restrict__ in, uint2* __restrict__ o, int n4) {
  int i = blockIdx.x * 256 + threadIdx.x;
  if (i < n4) {
    float4 v = in[i];
    uint2 r;
    r.x = (unsigned int)f2bf(v.x) | ((unsigned int)f2bf(v.y) << 16);
    r.y = (unsigned int)f2bf(v.z) | ((unsigned int)f2bf(v.w) << 16);
    o[i] = r;
  }
}

// ---- transpose+cast: in [R][C] f32 -> out [C][R] bf16
__global__ void transp_cast(const float* __restrict__ in, unsigned short* __restrict__ outT,
                            int R, int C) {
  __shared__ unsigned short t[64][65];
  int nbc = C >> 6;
  int tc = blockIdx.x % nbc, tr = blockIdx.x / nbc;
  int r0 = tr << 6, c0 = tc << 6;
  for (int i = threadIdx.x; i < 4096; i += 256) {
    int r = i >> 6, c = i & 63;
    t[c][r] = f2bf(in[(size_t)(r0 + r) * C + c0 + c]);
  }
  __syncthreads();
  for (int i = threadIdx.x; i < 4096; i += 256) {
    int c = i >> 6, r = i & 63;
    outT[(size_t)(c0 + c) * R + r0 + r] = t[c][r];
  }
}

// ---- pack h0 into tagged u32 buffer (tag = 0)
__global__ void pack_h0(const float* __restrict__ in, unsigned int* __restrict__ o) {
  int i = blockIdx.x * 256 + threadIdx.x;
  o[i] = (unsigned int)f2bf(in[i]);
}

// ---- Phase 1: xw packed as [t][cl][jw][r][jc][g] bf16 (u64 of 4 gates per cell)
#define BM 128
#define BN 128
#define BK 64

__launch_bounds__(256, 2)
__global__ void gemm_xw(const unsigned short* __restrict__ A,   // [32768][1024] bf16 (m = n*T+t)
                        const unsigned short* __restrict__ B,   // [4096][1024] bf16 (WxT)
                        const float* __restrict__ bias,         // [4096]
                        unsigned short* __restrict__ C)         // [1024][8][32][4][32][4] bf16
{
  __shared__ alignas(16) unsigned short As[BM * BK];
  __shared__ alignas(16) unsigned short Bs[BN * BK];
  int bid = blockIdx.x;
  int swz = (bid & 7) * 1024 + (bid >> 3);
  int grp = swz >> 8;
  int loc = swz & 255;
  int tm = (grp << 3) + (loc & 7);
  int tn = loc >> 3;
  int tid = threadIdx.x;
  int w = tid >> 6, lane = tid & 63;
  int wr = w >> 1, wc = w & 1;

  f32x4 acc[4][4] = {};

  const size_t rowA0 = (size_t)tm * BM;
  const size_t colB0 = (size_t)tn * BN;

  for (int k0 = 0; k0 < DD; k0 += BK) {
    #pragma unroll
    for (int i = 0; i < 4; ++i) {
      int chunk = w * 4 + i;
      int p = chunk * 1024 + lane * 16;
      int row = p >> 7;
      int bo = p & 127;
      int gb = bo ^ ((row & 7) << 4);
      const char* ga = (const char*)(A + (rowA0 + row) * DD + k0) + gb;
      __builtin_amdgcn_global_load_lds((gas_cp)ga, (las_p)((char*)As + chunk * 1024), 16, 0, 0);
      const char* gB = (const char*)(B + (colB0 + row) * DD + k0) + gb;
      __builtin_amdgcn_global_load_lds((gas_cp)gB, (las_p)((char*)Bs + chunk * 1024), 16, 0, 0);
    }
    __syncthreads();

    #pragma unroll
    for (int ks = 0; ks < 2; ++ks) {
      bf16x8 af[4], bfr[4];
      #pragma unroll
      for (int mi = 0; mi < 4; ++mi) {
        int row = wr * 64 + mi * 16 + (lane & 15);
        int kb = (ks * 32 + ((lane >> 4) << 3)) * 2;
        af[mi] = *(const bf16x8*)((const char*)As + row * 128 + (kb ^ ((row & 7) << 4)));
      }
      #pragma unroll
      for (int ni = 0; ni < 4; ++ni) {
        int row = wc * 64 + ni * 16 + (lane & 15);
        int kb = (ks * 32 + ((lane >> 4) << 3)) * 2;
        bfr[ni] = *(const bf16x8*)((const char*)Bs + row * 128 + (kb ^ ((row & 7) << 4)));
      }
      #pragma unroll
      for (int mi = 0; mi < 4; ++mi)
        #pragma unroll
        for (int ni = 0; ni < 4; ++ni)
          acc[mi][ni] = __builtin_amdgcn_mfma_f32_16x16x32_bf16(af[mi], bfr[ni], acc[mi][ni], 0, 0, 0);
    }
    __syncthreads();
  }

  #pragma unroll
  for (int ni = 0; ni < 4; ++ni) {
    int col = (int)colB0 + wc * 64 + ni * 16 + (lane & 15);
    float bb = bias[col];
    int g = col >> 10, J = col & 1023;
    int jw2 = J >> 5, jc2 = J & 31;
    #pragma unroll
    for (int mi = 0; mi < 4; ++mi) {
      #pragma unroll
      for (int r = 0; r < 4; ++r) {
        size_t row = rowA0 + wr * 64 + mi * 16 + ((lane >> 4) << 2) + r;  // m = n*T + t
        size_t n2 = row >> 10, t2 = row & 1023;
        size_t cl = n2 >> 2, rr = n2 & 3;
        C[((((t2 * 8 + cl) * 32 + jw2) * 4 + rr) * 32 + jc2) * 4 + g] = f2bf(acc[mi][ni][r] + bb);
      }
    }
  }
}

// ---- Phase 2: 8 XCD-local clusters x 4 samples, 256 wgs x 512 threads.
// Best-measured protocol (r14, lstm_rec 3.64 ms):
//  - self-timed tagged h (tag16|bf16 u32), agent-scope relaxed atomic stores
//  - per-producer chunked poll+MFMA pipeline: each 32-k chunk maps to ONE
//    producer wg; blocking-poll chunk0, then MFMA(chunk k) overlaps
//    resolve+prefetch(chunk k+1) -> no head-of-line blocking on stragglers
//  - alternating sc0 / sc0+sc1 poll cadence with s_sleep(1) backoff
//  - epilogue spread over all 8 waves (16 cells each, lanes 0-15)
// Verified dead ends (do not revisit): counted vmcnt (r10/r15: issue-order
// bugs/crash), always-sc1 (r13: +0.55 ms), tail chunk0 prefetch (r16: +0.25),
// 2-group stagger (r17: +1.6), flag protocols (r6/r9), LDS seq counters (r12).
#define LDA0(dst, ptr, off) asm volatile("global_load_dwordx2 %0, %1, off offset:" #off " sc0" : "=v"(dst) : "v"(ptr))
#define LDA1(dst, ptr, off) asm volatile("global_load_dwordx2 %0, %1, off offset:" #off " sc0 sc1" : "=v"(dst) : "v"(ptr))
#define LDW(dst, addr, off) asm volatile("global_load_dwordx4 %0, %1, off offset:" #off : "=v"(dst) : "v"(addr))

// blocking poll of one 4-u64 chunk (alternating sc0 / sc0+sc1 cadence)
#define POLLCHUNK(r0, r1, r2, r3, o0, o1, o2, o3)                              \
  { int rc_ = 0;                                                               \
    for (;;) {                                                                 \
      if (!(rc_ & 1)) { LDA0(r0,hq,o0); LDA0(r1,hq,o1); LDA0(r2,hq,o2); LDA0(r3,hq,o3); } \
      else            { LDA1(r0,hq,o0); LDA1(r1,hq,o1); LDA1(r2,hq,o2); LDA1(r3,hq,o3); } \
      asm volatile("s_waitcnt vmcnt(0)");                                      \
      __builtin_amdgcn_sched_barrier(0);                                       \
      unsigned long long bad_ = ((r0 & M64) ^ pat) | ((r1 & M64) ^ pat) |      \
                                ((r2 & M64) ^ pat) | ((r3 & M64) ^ pat);       \
      if (!__any(bad_ != 0)) break;                                            \
      __builtin_amdgcn_s_sleep(1);                                             \
      ++rc_;                                                                   \
    } }

// resolve a previously-prefetched chunk (full drain), fall back to poll
#define RESOLVECHUNK(r0, r1, r2, r3, o0, o1, o2, o3)                           \
  { asm volatile("s_waitcnt vmcnt(0)");                                        \
    __builtin_amdgcn_sched_barrier(0);                                         \
    unsigned long long bad_ = ((r0 & M64) ^ pat) | ((r1 & M64) ^ pat) |        \
                              ((r2 & M64) ^ pat) | ((r3 & M64) ^ pat);         \
    if (__any(bad_ != 0)) {                                                    \
      __builtin_amdgcn_s_sleep(1);                                             \
      POLLCHUNK(r0, r1, r2, r3, o0, o1, o2, o3)                                \
    } }

#define PREFCHUNK(r0, r1, r2, r3, o0, o1, o2, o3)                              \
  { LDA0(r0,hq,o0); LDA0(r1,hq,o1); LDA0(r2,hq,o2); LDA0(r3,hq,o3); }

__launch_bounds__(512, 1)
__global__ void lstm_rec(const unsigned long long* __restrict__ xw,  // [1024][8][32][128] u64
                         const unsigned short* __restrict__ WhT,     // [4096][1024] bf16
                         unsigned int* __restrict__ hbuf,            // [2][8][4][1024] u32 tagged
                         float* __restrict__ out)                    // [32][1024][1024] f32
{
  __shared__ float red[2][8][4][128];   // [par][kq][sample][gatecol] : 32 KB

  const int bid = blockIdx.x;
  const int cl = bid & 7;          // cluster (XCD via round-robin, perf-only)
  const int jw = bid >> 3;         // wg-in-cluster: h-cols jw*32..+32
  const int j0 = jw * 32;
  const int tid = threadIdx.x;
  const int lane = tid & 63;
  const int kq = tid >> 6;         // wave = K-eighth (128 k)
  const int l15 = lane & 15;
  const int q4 = lane >> 4;

  // ---- Wh slice -> registers via asm loads, once
  bf16x8 Bf[8][4];
  #pragma unroll
  for (int tile = 0; tile < 8; ++tile) {
    int cc = tile * 16 + l15;
    int gcol = (cc >> 5) * 1024 + j0 + (cc & 31);
    const unsigned short* wb = WhT + (size_t)gcol * HH + kq * 128 + q4 * 8;
    LDW(Bf[tile][0], wb, 0);
    LDW(Bf[tile][1], wb, 64);
    LDW(Bf[tile][2], wb, 128);
    LDW(Bf[tile][3], wb, 192);
  }
  asm volatile("s_waitcnt vmcnt(0)");

  const bool ld = (l15 < 4);            // 16 loading lanes per wave
  const int r4row = lane & 3;
  const bool ep = (lane < 16);          // epilogue lanes: 16 cells per wave
  const int ecell = kq * 16 + l15;      // 0..127
  const int er = ecell >> 5, ej = ecell & 31;
  float c = 0.f;
  const unsigned long long M64 = 0xFFFF0000FFFF0000ULL;

  unsigned long long u0=0,u1=0,u2=0,u3=0,u4=0,u5=0,u6=0,u7=0,
                     u8=0,u9=0,u10=0,u11=0,u12=0,u13=0,u14=0,u15=0;

  // prime xw prefetch for t=0
  unsigned long long xq = 0;
  if (ep) xq = xw[(((size_t)0 * 8 + cl) * 32 + jw) * 128 + ecell];

  #pragma unroll 1
  for (int t = 0; t < TT; ++t) {
    const int par = t & 1;
    const unsigned int* hc = hbuf + (size_t)par * 32768 + cl * 4096;
    unsigned int* hn = hbuf + (size_t)(par ^ 1) * 32768 + cl * 4096;

    const unsigned long long pat =
        ((unsigned long long)(unsigned)t << 16) | ((unsigned long long)(unsigned)t << 48);
    const unsigned long long* hq =
        (const unsigned long long*)(hc + (size_t)r4row * 1024 + kq * 128 + q4 * 8);

    f32x4 acc[8] = {};
    {
      uint32x4 wv;
      #define KSTEP(ks, a0, a1, a2, a3)                                              \
        wv[0] = __builtin_amdgcn_perm((unsigned)((a0) >> 32), (unsigned)(a0), 0x05040100u); \
        wv[1] = __builtin_amdgcn_perm((unsigned)((a1) >> 32), (unsigned)(a1), 0x05040100u); \
        wv[2] = __builtin_amdgcn_perm((unsigned)((a2) >> 32), (unsigned)(a2), 0x05040100u); \
        wv[3] = __builtin_amdgcn_perm((unsigned)((a3) >> 32), (unsigned)(a3), 0x05040100u); \
        { bf16x8 av = __builtin_bit_cast(bf16x8, wv);                                \
          _Pragma("unroll")                                                          \
          for (int tile = 0; tile < 8; ++tile)                                       \
            acc[tile] = __builtin_amdgcn_mfma_f32_16x16x32_bf16(av, Bf[tile][ks], acc[tile], 0, 0, 0); }

      // chunk 0 (producer wg kq*4+0): blocking poll, then prefetch chunk 1
      if (ld) {
        POLLCHUNK(u0, u1, u2, u3, 0, 8, 16, 24)
        PREFCHUNK(u4, u5, u6, u7, 128, 136, 144, 152)
      }
      KSTEP(0, u0, u1, u2, u3)

      if (ld) {
        RESOLVECHUNK(u4, u5, u6, u7, 128, 136, 144, 152)
        PREFCHUNK(u8, u9, u10, u11, 256, 264, 272, 280)
      }
      KSTEP(1, u4, u5, u6, u7)

      if (ld) {
        RESOLVECHUNK(u8, u9, u10, u11, 256, 264, 272, 280)
        PREFCHUNK(u12, u13, u14, u15, 384, 392, 400, 408)
      }
      KSTEP(2, u8, u9, u10, u11)

      if (ld) {
        RESOLVECHUNK(u12, u13, u14, u15, 384, 392, 400, 408)
      }
      KSTEP(3, u12, u13, u14, u15)
      #undef KSTEP
    }

    // ---- prefetch NEXT step's xw (completes during epilogue/sync)
    unsigned long long xq_n = 0;
    if (ep) {
      int tp = (t + 1 < TT) ? t + 1 : 0;
      xq_n = xw[(((size_t)tp * 8 + cl) * 32 + jw) * 128 + ecell];
    }

    if (q4 == 0) {
      #pragma unroll
      for (int tile = 0; tile < 8; ++tile)
        #pragma unroll
        for (int rg = 0; rg < 4; ++rg)
          red[par][kq][rg][tile * 16 + l15] = acc[tile][rg];
    }
    __syncthreads();

    // ---- epilogue: spread over all 8 waves, 16 cells each (lanes 0-15)
    if (ep) {
      float s0 = 0.f, s1 = 0.f, s2 = 0.f, s3 = 0.f;
      #pragma unroll
      for (int k2 = 0; k2 < 8; ++k2) {
        s0 += red[par][k2][er][ej];
        s1 += red[par][k2][er][32 + ej];
        s2 += red[par][k2][er][64 + ej];
        s3 += red[par][k2][er][96 + ej];
      }
      float ai  = s0 + bf2f((unsigned short)xq);
      float af_ = s1 + bf2f((unsigned short)(xq >> 16));
      float ao  = s2 + bf2f((unsigned short)(xq >> 32));
      float ag  = s3 + bf2f((unsigned short)(xq >> 48));
      float ig = sigm(ai), fg = sigm(af_), og = sigm(ao);
      float gg = tanh_f(ag);
      c = fg * c + ig * gg;
      float hv = og * tanh_f(c);

      unsigned int hp = (unsigned int)f2bf(hv) | ((unsigned int)(t + 1) << 16);
      __hip_atomic_store(hn + (size_t)er * 1024 + j0 + ej, hp,
                         __ATOMIC_RELAXED, __HIP_MEMORY_SCOPE_AGENT);
      out[((size_t)(cl * 4 + er) * TT + t) * HH + j0 + ej] = hv;
    }
    xq = xq_n;
  }
}

extern "C" void kernel_launch(void* const* d_in, const int* in_sizes, int n_in,
                              void* d_out, int out_size, void* d_ws, size_t ws_size,
                              hipStream_t stream) {
  (void)in_sizes; (void)n_in; (void)out_size;
  const float* x  = (const float*)d_in[0];
  const float* h0 = (const float*)d_in[1];
  const float* Wx = (const float*)d_in[2];
  const float* Wh = (const float*)d_in[3];
  const float* b  = (const float*)d_in[4];
  float* out = (float*)d_out;

  char* ws = (char*)d_ws;
  size_t o_xw  = 0;
  size_t o_xbf = o_xw  + (size_t)32768 * 4096 * 2;  // xw   : 268435456 B
  size_t o_wxT = o_xbf + (size_t)32768 * 1024 * 2;  // xbf  :  67108864 B
  size_t o_whT = o_wxT + (size_t)4096 * 1024 * 2;   // WxT  :   8388608 B
  size_t o_hb  = o_whT + (size_t)4096 * 1024 * 2;   // WhT  :   8388608 B
  size_t need  = o_hb  + (size_t)2 * 32768 * 4;     // hbuf :    262144 B
  if (ws_size < need) {
    fprintf(stderr, "kernel_launch: ws_size %zu < needed %zu\n", ws_size, need);
    return;
  }
  unsigned short* xw  = (unsigned short*)(ws + o_xw);
  unsigned short* xbf = (unsigned short*)(ws + o_xbf);
  unsigned short* wxT = (unsigned short*)(ws + o_wxT);
  unsigned short* whT = (unsigned short*)(ws + o_whT);
  unsigned int*   hb  = (unsigned int*)(ws + o_hb);

  // kill stale tags from previous graph replay, then write h0 with tag 0
  hipMemsetAsync(hb, 0xFF, (size_t)2 * 32768 * 4, stream);
  pack_h0<<<128, 256, 0, stream>>>(h0, hb);
  cast_bf4<<<32768, 256, 0, stream>>>((const float4*)x, (uint2*)xbf, 33554432 / 4);
  transp_cast<<<1024, 256, 0, stream>>>(Wx, wxT, 1024, 4096);
  transp_cast<<<1024, 256, 0, stream>>>(Wh, whT, 1024, 4096);
  gemm_xw<<<8192, 256, 0, stream>>>(xbf, wxT, b, xw);

  void* args[] = { (void*)&xw, (void*)&whT, (void*)&hb, (void*)&out };
  hipLaunchCooperativeKernel(lstm_rec, dim3(256), dim3(512), args, 0, stream);
}